// Round 1
// baseline (312.354 us; speedup 1.0000x reference)
//
#include <hip/hip_runtime.h>
#include <stdint.h>

#define B_ 8
#define S_ 2048
#define D_ 512
#define U_ 512
#define M_TOTAL (B_*S_)   // 16384
#define NPROJ (2*U_)      // 1024

typedef __attribute__((ext_vector_type(8))) short bf16x8;
typedef __attribute__((ext_vector_type(4))) float f32x4;

__device__ __forceinline__ uint16_t f2bf_rn(float f){
  uint32_t u = __builtin_bit_cast(uint32_t, f);
  u += 0x7fffu + ((u>>16)&1u);
  return (uint16_t)(u>>16);
}
__device__ __forceinline__ float bf2f(uint16_t h){
  uint32_t u = ((uint32_t)h)<<16;
  return __builtin_bit_cast(float, u);
}
// split f into hi (truncate) + lo (truncate of residual): f ~= hi + lo, err ~2^-16|f|
__device__ __forceinline__ void splitf(float f, uint16_t& hi, uint16_t& lo){
  uint32_t u = __builtin_bit_cast(uint32_t, f);
  hi = (uint16_t)(u>>16);
  float fh = __builtin_bit_cast(float, u & 0xffff0000u);
  float r = f - fh;
  lo = (uint16_t)(__builtin_bit_cast(uint32_t, r) >> 16);
}

// ---- prep: WT[u][d] = split(W[d][u]); u<512 -> Ww, else Uw ----
__global__ __launch_bounds__(256) void prep_w(const float* __restrict__ Ww,
                                              const float* __restrict__ Uw,
                                              uint16_t* __restrict__ WThi,
                                              uint16_t* __restrict__ WTlo){
  int idx = blockIdx.x*256 + threadIdx.x;   // 0 .. 1024*512-1
  int u = idx >> 9;
  int d = idx & 511;
  float v = (u < U_) ? Ww[d*U_ + u] : Uw[d*U_ + (u-U_)];
  uint16_t hi, lo; splitf(v, hi, lo);
  WThi[idx] = hi; WTlo[idx] = lo;
}

// ---- prep: XT[b][d][s] = bf16(X[b][s][d]) ----
__global__ __launch_bounds__(256) void prep_xt(const float* __restrict__ X,
                                               uint16_t* __restrict__ XT){
  __shared__ float tile[32][33];
  int b = blockIdx.z;
  int s0 = blockIdx.x * 32;
  int d0 = blockIdx.y * 32;
  int tid = threadIdx.x;
  int tr = tid >> 5;   // 0..7
  int tc = tid & 31;
  const float* Xb = X + (size_t)b*S_*D_;
#pragma unroll
  for (int i = 0; i < 32; i += 8)
    tile[tr+i][tc] = Xb[(size_t)(s0+tr+i)*D_ + d0+tc];
  __syncthreads();
  uint16_t* XTb = XT + (size_t)b*D_*S_;
#pragma unroll
  for (int i = 0; i < 32; i += 8)
    XTb[(size_t)(d0+tr+i)*S_ + s0+tc] = f2bf_rn(tile[tc][tr+i]);
}

// ---- unified NT GEMM: C[m][n] = sum_k A[m][k]*B[n][k] ----
#define MODE_PROJ 0    // A fp32 (split on fly), B pre-split bf16 hi/lo, 3-pass, +bias
#define MODE_SCORES 1  // A fp32, B fp32, both split on fly, 3-pass
#define MODE_PV 2      // A bf16, B bf16, 1-pass

template<int MODE>
__global__ __launch_bounds__(256) void gemm_nt(
    const char* __restrict__ Abase, long long strideA,
    const char* __restrict__ Bbase, long long strideB,
    const char* __restrict__ B2base,
    float* __restrict__ Cbase, long long strideC,
    const float* __restrict__ biasW, const float* __restrict__ biasU,
    int lda, int ldb, int ldc, int KD)
{
  constexpr int LDK = 48;                      // 32 + 16 pad (96B row stride)
  constexpr int NB = (MODE==MODE_PV) ? 2 : 4;
  __shared__ __align__(16) uint16_t lds[NB][128][LDK];

  uint16_t (*pAhi)[LDK] = lds[0];
  uint16_t (*pAlo)[LDK] = lds[(NB==4)?1:0];
  uint16_t (*pBhi)[LDK] = lds[(NB==4)?2:1];
  uint16_t (*pBlo)[LDK] = lds[(NB==4)?3:1];

  const int z  = blockIdx.z;
  const int m0 = blockIdx.y * 128;
  const int n0 = blockIdx.x * 128;

  const char* Ab = Abase + strideA*z;
  const char* Bb = Bbase + strideB*z;
  float* C = Cbase + strideC*z;

  const int t = threadIdx.x;
  const int sr = t >> 1;            // staging row 0..127
  const int sc = (t & 1) << 4;      // staging col 0/16
  const int lane = t & 63;
  const int wave = t >> 6;
  const int wr = (wave >> 1) << 6;
  const int wc = (wave & 1) << 6;
  const int fr = lane & 15;
  const int fg = lane >> 4;

  f32x4 acc[4][4];
#pragma unroll
  for (int i=0;i<4;i++)
#pragma unroll
    for (int j=0;j<4;j++) acc[i][j] = (f32x4){0.f,0.f,0.f,0.f};

  for (int kk = 0; kk < KD; kk += 32) {
    __syncthreads();
    // ---- stage A tile [128 x 32] ----
    if constexpr (MODE != MODE_PV) {
      const float* src = (const float*)Ab + (size_t)(m0+sr)*lda + kk + sc;
      float vv[16];
      *(float4*)(vv+0)  = *(const float4*)(src+0);
      *(float4*)(vv+4)  = *(const float4*)(src+4);
      *(float4*)(vv+8)  = *(const float4*)(src+8);
      *(float4*)(vv+12) = *(const float4*)(src+12);
#pragma unroll
      for (int q=0;q<4;q++){
        uint16_t h[4], l[4];
#pragma unroll
        for (int j=0;j<4;j++) splitf(vv[4*q+j], h[j], l[j]);
        *(ushort4*)&pAhi[sr][sc+4*q] = make_ushort4(h[0],h[1],h[2],h[3]);
        *(ushort4*)&pAlo[sr][sc+4*q] = make_ushort4(l[0],l[1],l[2],l[3]);
      }
    } else {
      const uint16_t* src = (const uint16_t*)Ab + (size_t)(m0+sr)*lda + kk + sc;
      *(uint4*)&pAhi[sr][sc+0] = *(const uint4*)(src+0);
      *(uint4*)&pAhi[sr][sc+8] = *(const uint4*)(src+8);
    }
    // ---- stage B tile [128 x 32] ----
    if constexpr (MODE == MODE_SCORES) {
      const float* src = (const float*)Bb + (size_t)(n0+sr)*ldb + kk + sc;
      float vv[16];
      *(float4*)(vv+0)  = *(const float4*)(src+0);
      *(float4*)(vv+4)  = *(const float4*)(src+4);
      *(float4*)(vv+8)  = *(const float4*)(src+8);
      *(float4*)(vv+12) = *(const float4*)(src+12);
#pragma unroll
      for (int q=0;q<4;q++){
        uint16_t h[4], l[4];
#pragma unroll
        for (int j=0;j<4;j++) splitf(vv[4*q+j], h[j], l[j]);
        *(ushort4*)&pBhi[sr][sc+4*q] = make_ushort4(h[0],h[1],h[2],h[3]);
        *(ushort4*)&pBlo[sr][sc+4*q] = make_ushort4(l[0],l[1],l[2],l[3]);
      }
    } else if constexpr (MODE == MODE_PROJ) {
      const uint16_t* sh = (const uint16_t*)Bb + (size_t)(n0+sr)*ldb + kk + sc;
      const uint16_t* sl = (const uint16_t*)B2base + (size_t)(n0+sr)*ldb + kk + sc;
      *(uint4*)&pBhi[sr][sc+0] = *(const uint4*)(sh+0);
      *(uint4*)&pBhi[sr][sc+8] = *(const uint4*)(sh+8);
      *(uint4*)&pBlo[sr][sc+0] = *(const uint4*)(sl+0);
      *(uint4*)&pBlo[sr][sc+8] = *(const uint4*)(sl+8);
    } else {
      const uint16_t* src = (const uint16_t*)Bb + (size_t)(n0+sr)*ldb + kk + sc;
      *(uint4*)&pBhi[sr][sc+0] = *(const uint4*)(src+0);
      *(uint4*)&pBhi[sr][sc+8] = *(const uint4*)(src+8);
    }
    __syncthreads();

    // ---- fragments + MFMA ----
    bf16x8 aH[4], bH[4], aL[4], bL[4];
#pragma unroll
    for (int i=0;i<4;i++){
      aH[i] = *(const bf16x8*)&pAhi[wr + i*16 + fr][fg*8];
      bH[i] = *(const bf16x8*)&pBhi[wc + i*16 + fr][fg*8];
      if constexpr (MODE != MODE_PV) {
        aL[i] = *(const bf16x8*)&pAlo[wr + i*16 + fr][fg*8];
        bL[i] = *(const bf16x8*)&pBlo[wc + i*16 + fr][fg*8];
      }
    }
#pragma unroll
    for (int mi=0;mi<4;mi++)
#pragma unroll
      for (int ni=0;ni<4;ni++){
        acc[mi][ni] = __builtin_amdgcn_mfma_f32_16x16x32_bf16(aH[mi], bH[ni], acc[mi][ni], 0,0,0);
        if constexpr (MODE != MODE_PV) {
          acc[mi][ni] = __builtin_amdgcn_mfma_f32_16x16x32_bf16(aH[mi], bL[ni], acc[mi][ni], 0,0,0);
          acc[mi][ni] = __builtin_amdgcn_mfma_f32_16x16x32_bf16(aL[mi], bH[ni], acc[mi][ni], 0,0,0);
        }
      }
  }

  // ---- epilogue: C/D layout col=lane&15, row=(lane>>4)*4+reg ----
#pragma unroll
  for (int mi=0;mi<4;mi++)
#pragma unroll
    for (int ni=0;ni<4;ni++){
      int col = n0 + wc + ni*16 + fr;
      float bias = 0.f;
      if constexpr (MODE == MODE_PROJ) bias = (col < U_) ? biasW[col] : biasU[col - U_];
      int rowb = m0 + wr + mi*16 + fg*4;
      f32x4 a = acc[mi][ni];
#pragma unroll
      for (int r=0;r<4;r++)
        C[(size_t)(rowb+r)*ldc + col] = a[r] + bias;
    }
}

// ---- row softmax, P bf16 written in-place over the row's own fp32 storage ----
__global__ __launch_bounds__(256) void softmax_rows(float* __restrict__ SPbase)
{
  const long long row = (long long)blockIdx.y * S_ + blockIdx.x;
  float* Srow = SPbase + row * (long long)S_;
  const int t = threadIdx.x;
  const int lane = t & 63, wave = t >> 6;
  float4 x0 = *((const float4*)Srow + t*2);
  float4 x1 = *((const float4*)Srow + t*2 + 1);
  float v[8] = {x0.x,x0.y,x0.z,x0.w,x1.x,x1.y,x1.z,x1.w};
  float mx = v[0];
#pragma unroll
  for (int j=1;j<8;j++) mx = fmaxf(mx, v[j]);
#pragma unroll
  for (int off=1; off<64; off<<=1) mx = fmaxf(mx, __shfl_xor(mx, off));
  __shared__ float redm[4], reds[4];
  if (lane==0) redm[wave] = mx;
  __syncthreads();
  mx = fmaxf(fmaxf(redm[0],redm[1]), fmaxf(redm[2],redm[3]));
  float sum = 0.f;
#pragma unroll
  for (int j=0;j<8;j++){ v[j] = expf(v[j]-mx); sum += v[j]; }
#pragma unroll
  for (int off=1; off<64; off<<=1) sum += __shfl_xor(sum, off);
  if (lane==0) reds[wave] = sum;
  __syncthreads();
  sum = reds[0]+reds[1]+reds[2]+reds[3];
  float inv = 1.0f / sum;
  uint16_t o[8];
#pragma unroll
  for (int j=0;j<8;j++) o[j] = f2bf_rn(v[j]*inv);
  uint16_t* Prow = (uint16_t*)Srow;
  *((ushort4*)Prow + t*2)     = make_ushort4(o[0],o[1],o[2],o[3]);
  *((ushort4*)Prow + t*2 + 1) = make_ushort4(o[4],o[5],o[6],o[7]);
}

extern "C" void kernel_launch(void* const* d_in, const int* in_sizes, int n_in,
                              void* d_out, int out_size, void* d_ws, size_t ws_size,
                              hipStream_t stream)
{
  (void)in_sizes; (void)n_in; (void)out_size;
  const float* X  = (const float*)d_in[0];
  const float* Ww = (const float*)d_in[1];
  const float* Wb = (const float*)d_in[2];
  const float* Uw = (const float*)d_in[3];
  const float* Ub = (const float*)d_in[4];
  float* out = (float*)d_out;

  char* ws = (char*)d_ws;
  float* QK = (float*)ws;                                   // [16384][1024] f32
  size_t off = (size_t)M_TOTAL * NPROJ * 4;
  uint16_t* XT = (uint16_t*)(ws + off); off += (size_t)B_*D_*S_*2;   // [B][D][S] bf16
  uint16_t* WThi = (uint16_t*)(ws + off); off += (size_t)NPROJ*D_*2; // [1024][512]
  uint16_t* WTlo = (uint16_t*)(ws + off); off += (size_t)NPROJ*D_*2;
  char* SP = ws + off;                                      // g * [2048][2048] f32 (P bf16 aliased)
  size_t per_b = (size_t)S_*S_*4;
  int g = 8;
  while (g > 1 && off + per_b*(size_t)g > ws_size) g >>= 1;

  prep_w<<<dim3((NPROJ*D_)/256), 256, 0, stream>>>(Ww, Uw, WThi, WTlo);
  prep_xt<<<dim3(S_/32, D_/32, B_), 256, 0, stream>>>(X, XT);

  gemm_nt<MODE_PROJ><<<dim3(NPROJ/128, M_TOTAL/128, 1), 256, 0, stream>>>(
      (const char*)X, 0, (const char*)WThi, 0, (const char*)WTlo,
      QK, 0, Wb, Ub, D_, D_, NPROJ, D_);

  for (int b0 = 0; b0 < B_; b0 += g) {
    const char* Qbase = (const char*)(QK + (size_t)b0 * S_ * NPROJ);
    const char* Kbase = (const char*)(QK + (size_t)b0 * S_ * NPROJ + U_);
    gemm_nt<MODE_SCORES><<<dim3(S_/128, S_/128, g), 256, 0, stream>>>(
        Qbase, (long long)S_*NPROJ*4, Kbase, (long long)S_*NPROJ*4, nullptr,
        (float*)SP, (long long)S_*S_, nullptr, nullptr,
        NPROJ, NPROJ, S_, U_);
    softmax_rows<<<dim3(S_, g), 256, 0, stream>>>((float*)SP);
    gemm_nt<MODE_PV><<<dim3(D_/128, S_/128, g), 256, 0, stream>>>(
        (const char*)SP, (long long)S_*S_*4,
        (const char*)(XT + (size_t)b0 * D_ * S_), (long long)D_*S_*2, nullptr,
        out + (size_t)b0 * S_ * D_, (long long)S_*D_, nullptr, nullptr,
        2*S_, S_, D_, S_);
  }
}

// Round 2
// 236.023 us; speedup vs baseline: 1.3234x; 1.3234x over previous
//
#include <hip/hip_runtime.h>
#include <stdint.h>

#define B_ 8
#define S_ 2048
#define D_ 512
#define U_ 512
#define M_TOTAL (B_*S_)   // 16384
#define NPROJ (2*U_)      // 1024

typedef __attribute__((ext_vector_type(8))) short bf16x8;
typedef __attribute__((ext_vector_type(8))) _Float16 f16x8;
typedef __attribute__((ext_vector_type(4))) float f32x4;

__device__ __forceinline__ uint16_t f2bf_rn(float f){
  uint32_t u = __builtin_bit_cast(uint32_t, f);
  u += 0x7fffu + ((u>>16)&1u);
  return (uint16_t)(u>>16);
}
// split f into bf16 hi (truncate) + bf16 lo (truncate of residual)
__device__ __forceinline__ void splitf(float f, uint16_t& hi, uint16_t& lo){
  uint32_t u = __builtin_bit_cast(uint32_t, f);
  hi = (uint16_t)(u>>16);
  float fh = __builtin_bit_cast(float, u & 0xffff0000u);
  float r = f - fh;
  lo = (uint16_t)(__builtin_bit_cast(uint32_t, r) >> 16);
}
__device__ __forceinline__ uint16_t f2h(float f){
  return __builtin_bit_cast(uint16_t, (_Float16)f);
}

__device__ __forceinline__ void gload16(const void* g, void* l){
  __builtin_amdgcn_global_load_lds(
      (const __attribute__((address_space(1))) void*)g,
      (__attribute__((address_space(3))) void*)l, 16, 0, 0);
}

// stage a 128x32 uint16 tile (linear LDS) via global_load_lds width=16.
// src must point at (tile_row0, k0); ld = row stride in elements.
__device__ __forceinline__ void stage_tile(uint16_t (*tile)[32],
                                           const uint16_t* __restrict__ src,
                                           int ld, int t){
  const int wv = t >> 6;
#pragma unroll
  for (int h = 0; h < 2; ++h){
    int chunk = h*256 + t;           // 16B chunk index: row = chunk/4, col8 = chunk%4
    int row = chunk >> 2, c = (chunk & 3) << 3;
    gload16(src + (size_t)row*ld + c, (char*)tile + h*4096 + wv*1024);
  }
}

// ---- prep: WT[u][d] = split(W[d][u]); u<512 -> Ww, else Uw ----
__global__ __launch_bounds__(256) void prep_w(const float* __restrict__ Ww,
                                              const float* __restrict__ Uw,
                                              uint16_t* __restrict__ WThi,
                                              uint16_t* __restrict__ WTlo){
  int idx = blockIdx.x*256 + threadIdx.x;   // 0 .. 1024*512-1
  int u = idx >> 9;
  int d = idx & 511;
  float v = (u < U_) ? Ww[d*U_ + u] : Uw[d*U_ + (u-U_)];
  uint16_t hi, lo; splitf(v, hi, lo);
  WThi[idx] = hi; WTlo[idx] = lo;
}

// ---- prep: Xhi/Xlo bf16 row-major; XT[b][d][s] f16 transposed ----
__global__ __launch_bounds__(256) void prep_x(const float* __restrict__ X,
                                              uint16_t* __restrict__ Xhi,
                                              uint16_t* __restrict__ Xlo,
                                              uint16_t* __restrict__ XTf){
  __shared__ float tile[32][33];
  int b = blockIdx.z;
  int s0 = blockIdx.x * 32;
  int d0 = blockIdx.y * 32;
  int tid = threadIdx.x;
  int tr = tid >> 5;   // 0..7
  int tc = tid & 31;
  const float* Xb = X + (size_t)b*S_*D_;
#pragma unroll
  for (int i = 0; i < 32; i += 8){
    size_t off = (size_t)(s0+tr+i)*D_ + d0+tc;
    float v = Xb[off];
    tile[tr+i][tc] = v;
    uint16_t h, l; splitf(v, h, l);
    Xhi[(size_t)b*S_*D_ + off] = h;
    Xlo[(size_t)b*S_*D_ + off] = l;
  }
  __syncthreads();
  uint16_t* XTb = XTf + (size_t)b*D_*S_;
#pragma unroll
  for (int i = 0; i < 32; i += 8)
    XTb[(size_t)(d0+tr+i)*S_ + s0+tc] = f2h(tile[tc][tr+i]);
}

// ---- unified NT GEMM: C[m][n] = sum_k A[m][k]*B[n][k], 128x128 tile, BK=32 ----
#define MODE_PROJ 0    // A,B pre-split bf16 hi/lo, 3-pass, +bias, writes Q/K f16
#define MODE_SCORES 1  // A,B f16, 1-pass, writes fp32
#define MODE_PV 2      // A,B f16, 1-pass, writes fp32

template<int MODE>
__global__ __launch_bounds__(256) void gemm_nt(
    const uint16_t* __restrict__ A1, const uint16_t* __restrict__ A2,
    long long strideA,
    const uint16_t* __restrict__ B1, const uint16_t* __restrict__ B2,
    long long strideB,
    float* __restrict__ Cf, long long strideC,
    uint16_t* __restrict__ Qo, uint16_t* __restrict__ Ko,
    const float* __restrict__ biasW, const float* __restrict__ biasU,
    int lda, int ldb, int ldc, int KD)
{
  constexpr int NT = (MODE==MODE_PROJ) ? 4 : 2;
  __shared__ __align__(16) uint16_t lds[NT][128][32];

  const int z  = blockIdx.z;
  const int m0 = blockIdx.y * 128;
  const int n0 = blockIdx.x * 128;

  const uint16_t* Abase1 = A1 + strideA*z + (size_t)m0*lda;
  const uint16_t* Abase2 = (MODE==MODE_PROJ) ? A2 + (size_t)m0*lda : nullptr;
  const uint16_t* Bbase1 = B1 + strideB*z + (size_t)n0*ldb;
  const uint16_t* Bbase2 = (MODE==MODE_PROJ) ? B2 + (size_t)n0*ldb : nullptr;

  const int t = threadIdx.x;
  const int lane = t & 63;
  const int wave = t >> 6;
  const int wr = (wave >> 1) << 6;
  const int wc = (wave & 1) << 6;
  const int fr = lane & 15;
  const int fg = lane >> 4;

  f32x4 acc[4][4];
#pragma unroll
  for (int i=0;i<4;i++)
#pragma unroll
    for (int j=0;j<4;j++) acc[i][j] = (f32x4){0.f,0.f,0.f,0.f};

  for (int kk = 0; kk < KD; kk += 32) {
    __syncthreads();
    stage_tile(lds[0], Abase1 + kk, lda, t);
    if constexpr (MODE==MODE_PROJ) stage_tile(lds[1], Abase2 + kk, lda, t);
    stage_tile(lds[NT==4?2:1], Bbase1 + kk, ldb, t);
    if constexpr (MODE==MODE_PROJ) stage_tile(lds[3], Bbase2 + kk, ldb, t);
    __syncthreads();

    if constexpr (MODE==MODE_PROJ) {
      bf16x8 aH[4], bH[4], aL[4], bL[4];
#pragma unroll
      for (int i=0;i<4;i++){
        aH[i] = *(const bf16x8*)&lds[0][wr + i*16 + fr][fg*8];
        aL[i] = *(const bf16x8*)&lds[1][wr + i*16 + fr][fg*8];
        bH[i] = *(const bf16x8*)&lds[2][wc + i*16 + fr][fg*8];
        bL[i] = *(const bf16x8*)&lds[3][wc + i*16 + fr][fg*8];
      }
#pragma unroll
      for (int mi=0;mi<4;mi++)
#pragma unroll
        for (int ni=0;ni<4;ni++){
          acc[mi][ni] = __builtin_amdgcn_mfma_f32_16x16x32_bf16(aH[mi], bH[ni], acc[mi][ni], 0,0,0);
          acc[mi][ni] = __builtin_amdgcn_mfma_f32_16x16x32_bf16(aH[mi], bL[ni], acc[mi][ni], 0,0,0);
          acc[mi][ni] = __builtin_amdgcn_mfma_f32_16x16x32_bf16(aL[mi], bH[ni], acc[mi][ni], 0,0,0);
        }
    } else {
      f16x8 av[4], bv[4];
#pragma unroll
      for (int i=0;i<4;i++){
        av[i] = *(const f16x8*)&lds[0][wr + i*16 + fr][fg*8];
        bv[i] = *(const f16x8*)&lds[1][wc + i*16 + fr][fg*8];
      }
#pragma unroll
      for (int mi=0;mi<4;mi++)
#pragma unroll
        for (int ni=0;ni<4;ni++)
          acc[mi][ni] = __builtin_amdgcn_mfma_f32_16x16x32_f16(av[mi], bv[ni], acc[mi][ni], 0,0,0);
    }
  }

  // ---- epilogue: C/D layout col=lane&15, row=(lane>>4)*4+reg ----
#pragma unroll
  for (int mi=0;mi<4;mi++)
#pragma unroll
    for (int ni=0;ni<4;ni++){
      int col  = n0 + wc + ni*16 + fr;
      int rowb = m0 + wr + mi*16 + fg*4;
      f32x4 a = acc[mi][ni];
      if constexpr (MODE==MODE_PROJ){
        float bias = (col < U_) ? biasW[col] : biasU[col - U_];
        if (col < U_){
#pragma unroll
          for (int r=0;r<4;r++) Qo[(size_t)(rowb+r)*U_ + col] = f2h(a[r] + bias);
        } else {
#pragma unroll
          for (int r=0;r<4;r++) Ko[(size_t)(rowb+r)*U_ + col - U_] = f2h(a[r] + bias);
        }
      } else {
        float* C = Cf + strideC*z;
#pragma unroll
        for (int r=0;r<4;r++)
          C[(size_t)(rowb+r)*ldc + col] = a[r];
      }
    }
}

// ---- row softmax: read fp32 row, write P f16 in-place at row base ----
__global__ __launch_bounds__(256) void softmax_rows(float* __restrict__ SPbase)
{
  const long long row = (long long)blockIdx.y * S_ + blockIdx.x;
  float* Srow = SPbase + row * (long long)S_;
  const int t = threadIdx.x;
  const int lane = t & 63, wave = t >> 6;
  float4 x0 = *((const float4*)Srow + t*2);
  float4 x1 = *((const float4*)Srow + t*2 + 1);
  float v[8] = {x0.x,x0.y,x0.z,x0.w,x1.x,x1.y,x1.z,x1.w};
  float mx = v[0];
#pragma unroll
  for (int j=1;j<8;j++) mx = fmaxf(mx, v[j]);
#pragma unroll
  for (int off=1; off<64; off<<=1) mx = fmaxf(mx, __shfl_xor(mx, off));
  __shared__ float redm[4], reds[4];
  if (lane==0) redm[wave] = mx;
  __syncthreads();
  mx = fmaxf(fmaxf(redm[0],redm[1]), fmaxf(redm[2],redm[3]));
  float sum = 0.f;
#pragma unroll
  for (int j=0;j<8;j++){ v[j] = expf(v[j]-mx); sum += v[j]; }
#pragma unroll
  for (int off=1; off<64; off<<=1) sum += __shfl_xor(sum, off);
  if (lane==0) reds[wave] = sum;
  __syncthreads();
  sum = reds[0]+reds[1]+reds[2]+reds[3];
  float inv = 1.0f / sum;
  uint16_t o[8];
#pragma unroll
  for (int j=0;j<8;j++) o[j] = f2h(v[j]*inv);
  uint16_t* Prow = (uint16_t*)Srow;
  *((ushort4*)Prow + t*2)     = make_ushort4(o[0],o[1],o[2],o[3]);
  *((ushort4*)Prow + t*2 + 1) = make_ushort4(o[4],o[5],o[6],o[7]);
}

extern "C" void kernel_launch(void* const* d_in, const int* in_sizes, int n_in,
                              void* d_out, int out_size, void* d_ws, size_t ws_size,
                              hipStream_t stream)
{
  (void)in_sizes; (void)n_in; (void)out_size;
  const float* X  = (const float*)d_in[0];
  const float* Ww = (const float*)d_in[1];
  const float* Wb = (const float*)d_in[2];
  const float* Uw = (const float*)d_in[3];
  const float* Ub = (const float*)d_in[4];
  float* out = (float*)d_out;

  char* ws = (char*)d_ws;
  size_t off = 0;
  uint16_t* Xhi = (uint16_t*)(ws + off); off += (size_t)M_TOTAL*D_*2;  // 16.8 MB
  uint16_t* Xlo = (uint16_t*)(ws + off); off += (size_t)M_TOTAL*D_*2;
  uint16_t* XT  = (uint16_t*)(ws + off); off += (size_t)B_*D_*S_*2;    // f16 [B][D][S]
  uint16_t* WThi= (uint16_t*)(ws + off); off += (size_t)NPROJ*D_*2;
  uint16_t* WTlo= (uint16_t*)(ws + off); off += (size_t)NPROJ*D_*2;
  uint16_t* Qf  = (uint16_t*)(ws + off); off += (size_t)M_TOTAL*U_*2;  // f16 [M][512]
  uint16_t* Kf  = (uint16_t*)(ws + off); off += (size_t)M_TOTAL*U_*2;
  char* SP = ws + off;                       // g * [2048][2048] fp32 (P f16 aliased)
  size_t per_b = (size_t)S_*S_*4;
  int g = 8;
  while (g > 1 && off + per_b*(size_t)g > ws_size) g >>= 1;

  prep_w<<<dim3((NPROJ*D_)/256), 256, 0, stream>>>(Ww, Uw, WThi, WTlo);
  prep_x<<<dim3(S_/32, D_/32, B_), 256, 0, stream>>>(X, Xhi, Xlo, XT);

  gemm_nt<MODE_PROJ><<<dim3(NPROJ/128, M_TOTAL/128, 1), 256, 0, stream>>>(
      Xhi, Xlo, 0, WThi, WTlo, 0,
      nullptr, 0, Qf, Kf, Wb, Ub,
      D_, D_, 0, D_);

  for (int b0 = 0; b0 < B_; b0 += g) {
    gemm_nt<MODE_SCORES><<<dim3(S_/128, S_/128, g), 256, 0, stream>>>(
        Qf + (size_t)b0*S_*U_, nullptr, (long long)S_*U_,
        Kf + (size_t)b0*S_*U_, nullptr, (long long)S_*U_,
        (float*)SP, (long long)S_*S_, nullptr, nullptr, nullptr, nullptr,
        U_, U_, S_, U_);
    softmax_rows<<<dim3(S_, g), 256, 0, stream>>>((float*)SP);
    gemm_nt<MODE_PV><<<dim3(D_/128, S_/128, g), 256, 0, stream>>>(
        (const uint16_t*)SP, nullptr, 2LL*S_*S_,
        XT + (size_t)b0*D_*S_, nullptr, (long long)D_*S_,
        out + (size_t)b0*S_*D_, (long long)S_*D_, nullptr, nullptr, nullptr, nullptr,
        2*S_, S_, D_, S_);
  }
}

// Round 3
// 163.605 us; speedup vs baseline: 1.9092x; 1.4426x over previous
//
#include <hip/hip_runtime.h>
#include <stdint.h>

#define B_ 8
#define S_ 2048
#define D_ 512
#define U_ 512
#define M_TOTAL (B_*S_)   // 16384
#define NPROJ (2*U_)      // 1024

typedef __attribute__((ext_vector_type(8))) _Float16 f16x8;
typedef __attribute__((ext_vector_type(4))) float f32x4;

__device__ __forceinline__ uint16_t f2h(float f){
  return __builtin_bit_cast(uint16_t, (_Float16)f);
}

__device__ __forceinline__ void gload16(const void* g, void* l){
  __builtin_amdgcn_global_load_lds(
      (const __attribute__((address_space(1))) void*)g,
      (__attribute__((address_space(3))) void*)l, 16, 0, 0);
}

// Stage one half-tile [ROWS x 64] f16 into linear LDS, with the global source
// pre-swizzled so that LDS granule (row, g) holds global granule (row, g^(row&7)).
// ROWS=128 -> 2 loads/thread (16KB), ROWS=64 -> 1 load/thread (8KB).
template<int ROWS>
__device__ __forceinline__ void stage_half(char* lbase, const uint16_t* __restrict__ gpanel,
                                           int ld, int wv, int lane){
  int r0 = wv*8 + (lane>>3);
  int gs = ((lane&7) ^ (r0&7)) << 3;     // swizzled element offset within row
  gload16(gpanel + (size_t)r0*ld + gs, lbase + wv*1024);
  if constexpr (ROWS==128){
    gload16(gpanel + (size_t)(r0+64)*ld + gs, lbase + 8192 + wv*1024);
  }
}

// ---- prep: WT[u][d] = f16(W[d][u]); u<512 -> Ww, else Uw ----
__global__ __launch_bounds__(256) void prep_w(const float* __restrict__ Ww,
                                              const float* __restrict__ Uw,
                                              uint16_t* __restrict__ WT){
  int idx = blockIdx.x*256 + threadIdx.x;
  int u = idx >> 9;
  int d = idx & 511;
  float v = (u < U_) ? Ww[d*U_ + u] : Uw[d*U_ + (u-U_)];
  WT[idx] = f2h(v);
}

// ---- prep: Xf[b][s][d] f16 row-major; XT[b][d][s] f16 transposed ----
__global__ __launch_bounds__(256) void prep_x(const float* __restrict__ X,
                                              uint16_t* __restrict__ Xf,
                                              uint16_t* __restrict__ XT){
  __shared__ float tile[32][33];
  int b = blockIdx.z;
  int s0 = blockIdx.x * 32;
  int d0 = blockIdx.y * 32;
  int tid = threadIdx.x;
  int tr = tid >> 5;   // 0..7
  int tc = tid & 31;
  const float* Xb = X + (size_t)b*S_*D_;
#pragma unroll
  for (int i = 0; i < 32; i += 8){
    size_t off = (size_t)(s0+tr+i)*D_ + d0+tc;
    float v = Xb[off];
    tile[tr+i][tc] = v;
    Xf[(size_t)b*S_*D_ + off] = f2h(v);
  }
  __syncthreads();
  uint16_t* XTb = XT + (size_t)b*D_*S_;
#pragma unroll
  for (int i = 0; i < 32; i += 8)
    XTb[(size_t)(d0+tr+i)*S_ + s0+tc] = f2h(tile[tc][tr+i]);
}

// ---- 8-phase NT GEMM: C[m][n] = sum_k A[m][k]*B[n][k] ----
// BM x 256 tile, BK=64, 512 threads = 8 waves (2M x 4N), per-wave BM/2 x 64.
// LDS: 2 dbuf x {A-half0, A-half1, B-half0, B-half1}; halves split by rows.
// Phases per K-tile: (ks,nh) in {(0,0),(0,1),(1,0),(1,1)}; stage stagger:
// q0->A1(t+1), q1->B0(t+1), q2->B1(t+1), q3->A0(t+2); vmcnt(ALOADS) at q3 end.
#define MODE_PROJ 0    // writes Q/K f16 + bias
#define MODE_SCORES 1  // writes fp32
#define MODE_PV 2      // writes fp32

template<int MODE, int BM>
__global__ __launch_bounds__(512, 2) void gemm8p(
    const uint16_t* __restrict__ A, long long strideA, int lda,
    const uint16_t* __restrict__ Bp, long long strideB, int ldb,
    float* __restrict__ Cf, long long strideC, int ldc,
    uint16_t* __restrict__ Qo, uint16_t* __restrict__ Ko,
    const float* __restrict__ biasW, const float* __restrict__ biasU,
    int KD)
{
  constexpr int BMH   = BM/2;          // rows per A half (128 or 64)
  constexpr int MFR   = BMH/16;        // m-frags per wave (8 or 4)
  constexpr int AHALF = BMH*128;       // bytes per A half-tile
  constexpr int BHALF = 128*128;       // bytes per B half-tile
  constexpr int DSTR  = 2*AHALF + 2*BHALF;
  constexpr int ALOADS = (BMH==128) ? 2 : 1;
  __shared__ __align__(16) char smem[2*DSTR];

  const int z  = blockIdx.z;
  const int m0 = blockIdx.y * BM;
  const int n0 = blockIdx.x * 256;
  const uint16_t* Apan = A  + strideA*z + (size_t)m0*lda;
  const uint16_t* Bpan = Bp + strideB*z + (size_t)n0*ldb;

  const int t512 = threadIdx.x;
  const int wv   = t512 >> 6;
  const int lane = t512 & 63;
  const int wm   = wv >> 2;     // 0..1
  const int wn   = wv & 3;      // 0..3
  const int fr   = lane & 15;
  const int fg   = lane >> 4;
  const int sw   = fr & 7;      // read-side swizzle term

  const int NT = KD >> 6;

  auto Aslot = [&](int par, int h){ return smem + par*DSTR + h*AHALF; };
  auto Bslot = [&](int par, int h){ return smem + par*DSTR + 2*AHALF + h*BHALF; };

  // ---- prologue: A0(0), A1(0), B0(0), B1(0), A0(1) ----
  stage_half<BMH>(Aslot(0,0), Apan,                      lda, wv, lane);
  stage_half<BMH>(Aslot(0,1), Apan + (size_t)BMH*lda,    lda, wv, lane);
  stage_half<128>(Bslot(0,0), Bpan,                      ldb, wv, lane);
  stage_half<128>(Bslot(0,1), Bpan + (size_t)128*ldb,    ldb, wv, lane);
  if (NT > 1)
    stage_half<BMH>(Aslot(1,0), Apan + 64,               lda, wv, lane);
  if constexpr (ALOADS==2) asm volatile("s_waitcnt vmcnt(2)" ::: "memory");
  else                     asm volatile("s_waitcnt vmcnt(1)" ::: "memory");
  __builtin_amdgcn_s_barrier();

  f32x4 acc[MFR][4];
#pragma unroll
  for (int i=0;i<MFR;i++)
#pragma unroll
    for (int j=0;j<4;j++) acc[i][j] = (f32x4){0.f,0.f,0.f,0.f};

  for (int t = 0; t < NT; ++t){
    const int p = t & 1;
    const char* myA = Aslot(p, wm);
    const char* myB = Bslot(p, wn>>1);
    f16x8 af[MFR];

    auto rdA = [&](int ks){
#pragma unroll
      for (int mf=0; mf<MFR; ++mf)
        af[mf] = *(const f16x8*)(myA + (mf*16+fr)*128 + (((ks<<2)|fg) ^ sw)*16);
    };
    auto rdB = [&](int ks, int nh, f16x8& b0, f16x8& b1){
      int rb = (wn&1)*64 + nh*32 + fr;
      b0 = *(const f16x8*)(myB + rb*128      + (((ks<<2)|fg) ^ sw)*16);
      b1 = *(const f16x8*)(myB + (rb+16)*128 + (((ks<<2)|fg) ^ sw)*16);
    };
    auto mm = [&](int nh, f16x8 b0, f16x8 b1){
      __builtin_amdgcn_s_setprio(1);
#pragma unroll
      for (int mf=0; mf<MFR; ++mf){
        acc[mf][nh*2]   = __builtin_amdgcn_mfma_f32_16x16x32_f16(af[mf], b0, acc[mf][nh*2],   0,0,0);
        acc[mf][nh*2+1] = __builtin_amdgcn_mfma_f32_16x16x32_f16(af[mf], b1, acc[mf][nh*2+1], 0,0,0);
      }
      __builtin_amdgcn_s_setprio(0);
    };

    f16x8 b0, b1;
    // ---- phase 0: ks=0, nh=0; stage A1(t+1) ----
    rdA(0); rdB(0, 0, b0, b1);
    if (t+1 < NT)
      stage_half<BMH>(Aslot(p^1,1), Apan + (size_t)BMH*lda + (t+1)*64, lda, wv, lane);
    __builtin_amdgcn_s_barrier();
    mm(0, b0, b1);
    __builtin_amdgcn_s_barrier();
    // ---- phase 1: ks=0, nh=1; stage B0(t+1) ----
    rdB(0, 1, b0, b1);
    if (t+1 < NT)
      stage_half<128>(Bslot(p^1,0), Bpan + (t+1)*64, ldb, wv, lane);
    __builtin_amdgcn_s_barrier();
    mm(1, b0, b1);
    __builtin_amdgcn_s_barrier();
    // ---- phase 2: ks=1, nh=0; stage B1(t+1) ----
    rdA(1); rdB(1, 0, b0, b1);
    if (t+1 < NT)
      stage_half<128>(Bslot(p^1,1), Bpan + (size_t)128*ldb + (t+1)*64, ldb, wv, lane);
    __builtin_amdgcn_s_barrier();
    mm(0, b0, b1);
    __builtin_amdgcn_s_barrier();
    // ---- phase 3: ks=1, nh=1; stage A0(t+2); boundary vmcnt ----
    rdB(1, 1, b0, b1);
    if (t+2 < NT)
      stage_half<BMH>(Aslot(p,0), Apan + (t+2)*64, lda, wv, lane);
    __builtin_amdgcn_s_barrier();
    mm(1, b0, b1);
    if constexpr (ALOADS==2) asm volatile("s_waitcnt vmcnt(2)" ::: "memory");
    else                     asm volatile("s_waitcnt vmcnt(1)" ::: "memory");
    __builtin_amdgcn_s_barrier();
  }

  // ---- epilogue: C/D layout col=lane&15, row=(lane>>4)*4+reg ----
#pragma unroll
  for (int mf=0; mf<MFR; ++mf)
#pragma unroll
    for (int nf=0; nf<4; ++nf){
      int col  = n0 + wn*64 + nf*16 + fr;
      int rowb = m0 + wm*BMH + mf*16 + fg*4;
      f32x4 a = acc[mf][nf];
      if constexpr (MODE==MODE_PROJ){
        float bias = (col < U_) ? biasW[col] : biasU[col - U_];
        if (col < U_){
#pragma unroll
          for (int r=0;r<4;r++) Qo[(size_t)(rowb+r)*U_ + col] = f2h(a[r] + bias);
        } else {
#pragma unroll
          for (int r=0;r<4;r++) Ko[(size_t)(rowb+r)*U_ + col - U_] = f2h(a[r] + bias);
        }
      } else {
        float* C = Cf + strideC*z;
#pragma unroll
        for (int r=0;r<4;r++)
          C[(size_t)(rowb+r)*ldc + col] = a[r];
      }
    }
}

// ---- row softmax: read fp32 row, write P f16 in-place at row base ----
__global__ __launch_bounds__(256) void softmax_rows(float* __restrict__ SPbase)
{
  const long long row = (long long)blockIdx.y * S_ + blockIdx.x;
  float* Srow = SPbase + row * (long long)S_;
  const int t = threadIdx.x;
  const int lane = t & 63, wave = t >> 6;
  float4 x0 = *((const float4*)Srow + t*2);
  float4 x1 = *((const float4*)Srow + t*2 + 1);
  float v[8] = {x0.x,x0.y,x0.z,x0.w,x1.x,x1.y,x1.z,x1.w};
  float mx = v[0];
#pragma unroll
  for (int j=1;j<8;j++) mx = fmaxf(mx, v[j]);
#pragma unroll
  for (int off=1; off<64; off<<=1) mx = fmaxf(mx, __shfl_xor(mx, off));
  __shared__ float redm[4], reds[4];
  if (lane==0) redm[wave] = mx;
  __syncthreads();
  mx = fmaxf(fmaxf(redm[0],redm[1]), fmaxf(redm[2],redm[3]));
  float sum = 0.f;
#pragma unroll
  for (int j=0;j<8;j++){ v[j] = expf(v[j]-mx); sum += v[j]; }
#pragma unroll
  for (int off=1; off<64; off<<=1) sum += __shfl_xor(sum, off);
  if (lane==0) reds[wave] = sum;
  __syncthreads();
  sum = reds[0]+reds[1]+reds[2]+reds[3];
  float inv = 1.0f / sum;
  uint16_t o[8];
#pragma unroll
  for (int j=0;j<8;j++) o[j] = f2h(v[j]*inv);
  uint16_t* Prow = (uint16_t*)Srow;
  *((ushort4*)Prow + t*2)     = make_ushort4(o[0],o[1],o[2],o[3]);
  *((ushort4*)Prow + t*2 + 1) = make_ushort4(o[4],o[5],o[6],o[7]);
}

extern "C" void kernel_launch(void* const* d_in, const int* in_sizes, int n_in,
                              void* d_out, int out_size, void* d_ws, size_t ws_size,
                              hipStream_t stream)
{
  (void)in_sizes; (void)n_in; (void)out_size;
  const float* X  = (const float*)d_in[0];
  const float* Ww = (const float*)d_in[1];
  const float* Wb = (const float*)d_in[2];
  const float* Uw = (const float*)d_in[3];
  const float* Ub = (const float*)d_in[4];
  float* out = (float*)d_out;

  char* ws = (char*)d_ws;
  size_t off = 0;
  uint16_t* Xf = (uint16_t*)(ws + off); off += (size_t)M_TOTAL*D_*2;  // f16 [M][512]
  uint16_t* XT = (uint16_t*)(ws + off); off += (size_t)B_*D_*S_*2;    // f16 [B][512][2048]
  uint16_t* WT = (uint16_t*)(ws + off); off += (size_t)NPROJ*D_*2;    // f16 [1024][512]
  uint16_t* Qf = (uint16_t*)(ws + off); off += (size_t)M_TOTAL*U_*2;  // f16 [M][512]
  uint16_t* Kf = (uint16_t*)(ws + off); off += (size_t)M_TOTAL*U_*2;
  char* SP = ws + off;                       // g * [2048][2048] fp32 (P f16 aliased)
  size_t per_b = (size_t)S_*S_*4;
  int g = 8;
  while (g > 1 && off + per_b*(size_t)g > ws_size) g >>= 1;

  prep_w<<<dim3((NPROJ*D_)/256), 256, 0, stream>>>(Ww, Uw, WT);
  prep_x<<<dim3(S_/32, D_/32, B_), 256, 0, stream>>>(X, Xf, XT);

  gemm8p<MODE_PROJ,256><<<dim3(NPROJ/256, M_TOTAL/256, 1), 512, 0, stream>>>(
      Xf, 0, D_, WT, 0, D_,
      nullptr, 0, 0, Qf, Kf, Wb, Ub, D_);

  for (int b0 = 0; b0 < B_; b0 += g) {
    gemm8p<MODE_SCORES,256><<<dim3(S_/256, S_/256, g), 512, 0, stream>>>(
        Qf + (size_t)b0*S_*U_, (long long)S_*U_, U_,
        Kf + (size_t)b0*S_*U_, (long long)S_*U_, U_,
        (float*)SP, (long long)S_*S_, S_,
        nullptr, nullptr, nullptr, nullptr, U_);
    softmax_rows<<<dim3(S_, g), 256, 0, stream>>>((float*)SP);
    gemm8p<MODE_PV,128><<<dim3(D_/256, S_/128, g), 512, 0, stream>>>(
        (const uint16_t*)SP, 2LL*S_*S_, 2*S_,
        XT + (size_t)b0*D_*S_, (long long)D_*S_, S_,
        out + (size_t)b0*S_*D_, (long long)S_*D_, D_,
        nullptr, nullptr, nullptr, nullptr, S_);
  }
}

// Round 4
// 161.158 us; speedup vs baseline: 1.9382x; 1.0152x over previous
//
#include <hip/hip_runtime.h>
#include <stdint.h>

#define B_ 8
#define S_ 2048
#define D_ 512
#define U_ 512
#define M_TOTAL (B_*S_)   // 16384
#define NPROJ (2*U_)      // 1024
#define QBLK 64
#define KVBLK 64
#define NIT (S_/KVBLK)    // 32

typedef __attribute__((ext_vector_type(8))) _Float16 f16x8;
typedef __attribute__((ext_vector_type(4))) float f32x4;

__device__ __forceinline__ uint16_t f2h(float f){
  return __builtin_bit_cast(uint16_t, (_Float16)f);
}

__device__ __forceinline__ void gload16(const void* g, void* l){
  __builtin_amdgcn_global_load_lds(
      (const __attribute__((address_space(1))) void*)g,
      (__attribute__((address_space(3))) void*)l, 16, 0, 0);
}

// Stage one half-tile [ROWS x 64] f16 into linear LDS, global source pre-swizzled.
template<int ROWS>
__device__ __forceinline__ void stage_half(char* lbase, const uint16_t* __restrict__ gpanel,
                                           int ld, int wv, int lane){
  int r0 = wv*8 + (lane>>3);
  int gs = ((lane&7) ^ (r0&7)) << 3;
  gload16(gpanel + (size_t)r0*ld + gs, lbase + wv*1024);
  if constexpr (ROWS==128){
    gload16(gpanel + (size_t)(r0+64)*ld + gs, lbase + 8192 + wv*1024);
  }
}

// ---- prep: WT[u][d] = f16(W[d][u]); u<512 -> Ww, else Uw ----
__global__ __launch_bounds__(256) void prep_w(const float* __restrict__ Ww,
                                              const float* __restrict__ Uw,
                                              uint16_t* __restrict__ WT){
  int idx = blockIdx.x*256 + threadIdx.x;
  int u = idx >> 9;
  int d = idx & 511;
  float v = (u < U_) ? Ww[d*U_ + u] : Uw[d*U_ + (u-U_)];
  WT[idx] = f2h(v);
}

// ---- prep: Xf[b][s][d] f16 row-major; XT[b][d][s] f16 transposed ----
__global__ __launch_bounds__(256) void prep_x(const float* __restrict__ X,
                                              uint16_t* __restrict__ Xf,
                                              uint16_t* __restrict__ XT){
  __shared__ float tile[32][33];
  int b = blockIdx.z;
  int s0 = blockIdx.x * 32;
  int d0 = blockIdx.y * 32;
  int tid = threadIdx.x;
  int tr = tid >> 5;
  int tc = tid & 31;
  const float* Xb = X + (size_t)b*S_*D_;
#pragma unroll
  for (int i = 0; i < 32; i += 8){
    size_t off = (size_t)(s0+tr+i)*D_ + d0+tc;
    float v = Xb[off];
    tile[tr+i][tc] = v;
    Xf[(size_t)b*S_*D_ + off] = f2h(v);
  }
  __syncthreads();
  uint16_t* XTb = XT + (size_t)b*D_*S_;
#pragma unroll
  for (int i = 0; i < 32; i += 8)
    XTb[(size_t)(d0+tr+i)*S_ + s0+tc] = f2h(tile[tc][tr+i]);
}

// ---- 8-phase NT projection GEMM (from R3, PROJ mode only) ----
__global__ __launch_bounds__(512, 2) void gemm_proj(
    const uint16_t* __restrict__ A, int lda,
    const uint16_t* __restrict__ Bp, int ldb,
    uint16_t* __restrict__ Qo, uint16_t* __restrict__ Ko,
    const float* __restrict__ biasW, const float* __restrict__ biasU,
    int KD)
{
  constexpr int BMH   = 128;
  constexpr int MFR   = 8;
  constexpr int AHALF = BMH*128;
  constexpr int BHALF = 128*128;
  constexpr int DSTR  = 2*AHALF + 2*BHALF;
  __shared__ __align__(16) char smem[2*DSTR];

  const int m0 = blockIdx.y * 256;
  const int n0 = blockIdx.x * 256;
  const uint16_t* Apan = A  + (size_t)m0*lda;
  const uint16_t* Bpan = Bp + (size_t)n0*ldb;

  const int t512 = threadIdx.x;
  const int wv   = t512 >> 6;
  const int lane = t512 & 63;
  const int wm   = wv >> 2;
  const int wn   = wv & 3;
  const int fr   = lane & 15;
  const int fg   = lane >> 4;
  const int sw   = fr & 7;

  const int NT = KD >> 6;

  auto Aslot = [&](int par, int h){ return smem + par*DSTR + h*AHALF; };
  auto Bslot = [&](int par, int h){ return smem + par*DSTR + 2*AHALF + h*BHALF; };

  stage_half<128>(Aslot(0,0), Apan,                   lda, wv, lane);
  stage_half<128>(Aslot(0,1), Apan + (size_t)128*lda, lda, wv, lane);
  stage_half<128>(Bslot(0,0), Bpan,                   ldb, wv, lane);
  stage_half<128>(Bslot(0,1), Bpan + (size_t)128*ldb, ldb, wv, lane);
  if (NT > 1)
    stage_half<128>(Aslot(1,0), Apan + 64,            lda, wv, lane);
  asm volatile("s_waitcnt vmcnt(2)" ::: "memory");
  __builtin_amdgcn_s_barrier();

  f32x4 acc[MFR][4];
#pragma unroll
  for (int i=0;i<MFR;i++)
#pragma unroll
    for (int j=0;j<4;j++) acc[i][j] = (f32x4){0.f,0.f,0.f,0.f};

  for (int t = 0; t < NT; ++t){
    const int p = t & 1;
    const char* myA = Aslot(p, wm);
    const char* myB = Bslot(p, wn>>1);
    f16x8 af[MFR];

    auto rdA = [&](int ks){
#pragma unroll
      for (int mf=0; mf<MFR; ++mf)
        af[mf] = *(const f16x8*)(myA + (mf*16+fr)*128 + (((ks<<2)|fg) ^ sw)*16);
    };
    auto rdB = [&](int ks, int nh, f16x8& b0, f16x8& b1){
      int rb = (wn&1)*64 + nh*32 + fr;
      b0 = *(const f16x8*)(myB + rb*128      + (((ks<<2)|fg) ^ sw)*16);
      b1 = *(const f16x8*)(myB + (rb+16)*128 + (((ks<<2)|fg) ^ sw)*16);
    };
    auto mm = [&](int nh, f16x8 b0, f16x8 b1){
      __builtin_amdgcn_s_setprio(1);
#pragma unroll
      for (int mf=0; mf<MFR; ++mf){
        acc[mf][nh*2]   = __builtin_amdgcn_mfma_f32_16x16x32_f16(af[mf], b0, acc[mf][nh*2],   0,0,0);
        acc[mf][nh*2+1] = __builtin_amdgcn_mfma_f32_16x16x32_f16(af[mf], b1, acc[mf][nh*2+1], 0,0,0);
      }
      __builtin_amdgcn_s_setprio(0);
    };

    f16x8 b0, b1;
    rdA(0); rdB(0, 0, b0, b1);
    if (t+1 < NT)
      stage_half<128>(Aslot(p^1,1), Apan + (size_t)128*lda + (t+1)*64, lda, wv, lane);
    __builtin_amdgcn_s_barrier();
    mm(0, b0, b1);
    __builtin_amdgcn_s_barrier();
    rdB(0, 1, b0, b1);
    if (t+1 < NT)
      stage_half<128>(Bslot(p^1,0), Bpan + (t+1)*64, ldb, wv, lane);
    __builtin_amdgcn_s_barrier();
    mm(1, b0, b1);
    __builtin_amdgcn_s_barrier();
    rdA(1); rdB(1, 0, b0, b1);
    if (t+1 < NT)
      stage_half<128>(Bslot(p^1,1), Bpan + (size_t)128*ldb + (t+1)*64, ldb, wv, lane);
    __builtin_amdgcn_s_barrier();
    mm(0, b0, b1);
    __builtin_amdgcn_s_barrier();
    rdB(1, 1, b0, b1);
    if (t+2 < NT)
      stage_half<128>(Aslot(p,0), Apan + (t+2)*64, lda, wv, lane);
    __builtin_amdgcn_s_barrier();
    mm(1, b0, b1);
    asm volatile("s_waitcnt vmcnt(2)" ::: "memory");
    __builtin_amdgcn_s_barrier();
  }

#pragma unroll
  for (int mf=0; mf<MFR; ++mf)
#pragma unroll
    for (int nf=0; nf<4; ++nf){
      int col  = n0 + wn*64 + nf*16 + fr;
      int rowb = m0 + wm*128 + mf*16 + fg*4;
      f32x4 a = acc[mf][nf];
      float bias = (col < U_) ? biasW[col] : biasU[col - U_];
      if (col < U_){
#pragma unroll
        for (int r=0;r<4;r++) Qo[(size_t)(rowb+r)*U_ + col] = f2h(a[r] + bias);
      } else {
#pragma unroll
        for (int r=0;r<4;r++) Ko[(size_t)(rowb+r)*U_ + col - U_] = f2h(a[r] + bias);
      }
    }
}

// ---- fused flash attention: scores + online softmax + PV ----
// Block: 64 q-rows, one batch (bid&7 -> XCD pin). 8 waves.
// QK^T waves: qg=wv>>1 (16 q-rows), kh=wv&1 (32 kv cols, 2 frags).
// PV waves:   wm=wv>>2 (32 q-rows), wd=wv&3 (128 d cols).
__global__ __launch_bounds__(512, 2) void flash_attn(
    const uint16_t* __restrict__ Qf,   // [B*S][512] f16
    const uint16_t* __restrict__ Kf,   // [B*S][512] f16
    const uint16_t* __restrict__ XT,   // [B][512][2048] f16
    float* __restrict__ Out)           // [B*S][512] f32
{
  __shared__ __align__(16) uint16_t Ks[KVBLK][512];   // 64 KB (granule-swizzled)
  __shared__ __align__(16) uint16_t Vs[512][KVBLK];   // 64 KB (granule-swizzled, row=d)
  __shared__ __align__(16) float    Ss[QBLK][68];     // 17 KB
  __shared__ __align__(16) uint16_t Ps[QBLK][KVBLK];  // 8 KB (granule-swizzled)
  __shared__ float m_s[QBLK], l_s[QBLK], f_s[QBLK];

  const int bid   = blockIdx.x;
  const int batch = bid & 7;
  const int mblk  = bid >> 3;
  const int s0    = mblk * QBLK;

  const int t    = threadIdx.x;
  const int wv   = t >> 6;
  const int lane = t & 63;
  const int fr   = lane & 15;
  const int fg   = lane >> 4;
  const int qg = wv >> 1;
  const int kh = wv & 1;
  const int wm = wv >> 2;
  const int wd = wv & 3;

  const uint16_t* Qrow = Qf + ((size_t)batch*S_ + s0)*U_;
  const uint16_t* Krow = Kf + (size_t)batch*S_*U_;
  const uint16_t* Vt   = XT + (size_t)batch*D_*S_;

  // Q into registers in A-frag layout: qreg[kk] = Q[qg*16+fr][kk*32+fg*8 ..]
  f16x8 qreg[16];
#pragma unroll
  for (int kk=0; kk<16; ++kk)
    qreg[kk] = *(const f16x8*)(Qrow + (size_t)(qg*16+fr)*U_ + kk*32 + fg*8);

  auto stageK = [&](int ti){
    const uint16_t* src = Krow + (size_t)(ti*KVBLK)*U_;
#pragma unroll
    for (int i=0;i<8;++i){
      int r = i*8 + wv;
      gload16(src + (size_t)r*U_ + ((lane ^ (r&7))<<3),
              (char*)Ks + i*8192 + wv*1024);
    }
  };
  auto stageV = [&](int ti){
    const uint16_t* src = Vt + ti*KVBLK;
#pragma unroll
    for (int i=0;i<8;++i){
      int d = i*64 + wv*8 + (lane>>3);
      int g = lane & 7;
      gload16(src + (size_t)d*S_ + ((g ^ (d&7))<<3),
              (char*)Vs + i*8192 + wv*1024);
    }
  };

  stageK(0);
  if (t < QBLK){ m_s[t] = -3e38f; l_s[t] = 0.f; }
  f32x4 acc[2][8];
#pragma unroll
  for (int i=0;i<2;i++)
#pragma unroll
    for (int j=0;j<8;j++) acc[i][j] = (f32x4){0.f,0.f,0.f,0.f};
  asm volatile("s_waitcnt lgkmcnt(0)" ::: "memory");
  __builtin_amdgcn_s_barrier();

  for (int it=0; it<NIT; ++it){
    // V(t) in flight under QK^T
    stageV(it);
    // K(t) resident (8 newest outstanding = V(t))
    asm volatile("s_waitcnt vmcnt(8)" ::: "memory");

    f32x4 sfr0 = (f32x4){0.f,0.f,0.f,0.f};
    f32x4 sfr1 = (f32x4){0.f,0.f,0.f,0.f};
    __builtin_amdgcn_s_setprio(1);
#pragma unroll
    for (int kk=0; kk<16; ++kk){
      int gA = kk*4 + fg;
      int kr0 = kh*32 + fr;
      int kr1 = kh*32 + 16 + fr;
      f16x8 bv0 = *(const f16x8*)((const char*)Ks + kr0*1024 + ((gA ^ (kr0&7))<<4));
      f16x8 bv1 = *(const f16x8*)((const char*)Ks + kr1*1024 + ((gA ^ (kr1&7))<<4));
      sfr0 = __builtin_amdgcn_mfma_f32_16x16x32_f16(qreg[kk], bv0, sfr0, 0,0,0);
      sfr1 = __builtin_amdgcn_mfma_f32_16x16x32_f16(qreg[kk], bv1, sfr1, 0,0,0);
    }
    __builtin_amdgcn_s_setprio(0);
    // write S frags: row = qg*16+fg*4+r, col = kh*32 + {0,16} + fr
#pragma unroll
    for (int r=0;r<4;++r){
      Ss[qg*16 + fg*4 + r][kh*32 + fr]      = sfr0[r];
      Ss[qg*16 + fg*4 + r][kh*32 + 16 + fr] = sfr1[r];
    }
    asm volatile("s_waitcnt lgkmcnt(0)" ::: "memory");
    __builtin_amdgcn_s_barrier();

    // ---- online softmax: thread covers row r=t>>3, cols j*8..+8 ----
    {
      const int r = t >> 3, j = t & 7;
      float4 v0 = *(const float4*)&Ss[r][j*8];
      float4 v1 = *(const float4*)&Ss[r][j*8+4];
      float pm = fmaxf(fmaxf(fmaxf(v0.x,v0.y),fmaxf(v0.z,v0.w)),
                       fmaxf(fmaxf(v1.x,v1.y),fmaxf(v1.z,v1.w)));
      pm = fmaxf(pm, __shfl_xor(pm, 1));
      pm = fmaxf(pm, __shfl_xor(pm, 2));
      pm = fmaxf(pm, __shfl_xor(pm, 4));
      float mo = m_s[r];
      float mn = (pm > mo + 8.f) ? pm : mo;   // defer-max (T13)
      float p0 = __expf(v0.x-mn), p1 = __expf(v0.y-mn), p2 = __expf(v0.z-mn), p3 = __expf(v0.w-mn);
      float p4 = __expf(v1.x-mn), p5 = __expf(v1.y-mn), p6 = __expf(v1.z-mn), p7 = __expf(v1.w-mn);
      float sum = ((p0+p1)+(p2+p3)) + ((p4+p5)+(p6+p7));
      sum += __shfl_xor(sum, 1);
      sum += __shfl_xor(sum, 2);
      sum += __shfl_xor(sum, 4);
      if (j == 0){
        float f = __expf(mo - mn);
        f_s[r] = f;
        m_s[r] = mn;
        l_s[r] = l_s[r]*f + sum;
      }
      f16x8 pv;
      pv[0]=(_Float16)p0; pv[1]=(_Float16)p1; pv[2]=(_Float16)p2; pv[3]=(_Float16)p3;
      pv[4]=(_Float16)p4; pv[5]=(_Float16)p5; pv[6]=(_Float16)p6; pv[7]=(_Float16)p7;
      *(f16x8*)((char*)Ps + r*128 + ((j ^ (r&7))<<4)) = pv;
    }
    asm volatile("s_waitcnt lgkmcnt(0)" ::: "memory");
    __builtin_amdgcn_s_barrier();

    // ---- PV phase ----
    asm volatile("s_waitcnt vmcnt(0)" ::: "memory");   // V(t) landed
    if (it+1 < NIT) stageK(it+1);                      // lands under PV MFMA

    // O-rescale (skipped when no row updated its max)
    float fx[2][4];
#pragma unroll
    for (int mf=0; mf<2; ++mf)
#pragma unroll
      for (int r=0; r<4; ++r)
        fx[mf][r] = f_s[wm*32 + mf*16 + fg*4 + r];
    bool nr = (fx[0][0]!=1.f)|(fx[0][1]!=1.f)|(fx[0][2]!=1.f)|(fx[0][3]!=1.f)|
              (fx[1][0]!=1.f)|(fx[1][1]!=1.f)|(fx[1][2]!=1.f)|(fx[1][3]!=1.f);
    if (__any(nr)){
#pragma unroll
      for (int mf=0; mf<2; ++mf)
#pragma unroll
        for (int nf=0; nf<8; ++nf)
#pragma unroll
          for (int r=0; r<4; ++r)
            acc[mf][nf][r] *= fx[mf][r];
    }

    __builtin_amdgcn_s_setprio(1);
#pragma unroll
    for (int ks=0; ks<2; ++ks){
      int gP = ks*4 + fg;
      int q0 = wm*32 + fr;
      int q1 = wm*32 + 16 + fr;
      f16x8 pa0 = *(const f16x8*)((const char*)Ps + q0*128 + ((gP ^ (q0&7))<<4));
      f16x8 pa1 = *(const f16x8*)((const char*)Ps + q1*128 + ((gP ^ (q1&7))<<4));
#pragma unroll
      for (int nf=0; nf<8; ++nf){
        int d = wd*128 + nf*16 + fr;
        f16x8 bv = *(const f16x8*)((const char*)Vs + d*128 + ((gP ^ (d&7))<<4));
        acc[0][nf] = __builtin_amdgcn_mfma_f32_16x16x32_f16(pa0, bv, acc[0][nf], 0,0,0);
        acc[1][nf] = __builtin_amdgcn_mfma_f32_16x16x32_f16(pa1, bv, acc[1][nf], 0,0,0);
      }
    }
    __builtin_amdgcn_s_setprio(0);
    __builtin_amdgcn_s_barrier();   // end of iter: all PV reads done
  }

  // ---- epilogue: O /= l; write fp32 ----
  float linv[2][4];
#pragma unroll
  for (int mf=0; mf<2; ++mf)
#pragma unroll
    for (int r=0; r<4; ++r)
      linv[mf][r] = 1.0f / l_s[wm*32 + mf*16 + fg*4 + r];
  float* Ob = Out + ((size_t)batch*S_ + s0)*D_;
#pragma unroll
  for (int mf=0; mf<2; ++mf)
#pragma unroll
    for (int nf=0; nf<8; ++nf){
      int d = wd*128 + nf*16 + fr;
#pragma unroll
      for (int r=0; r<4; ++r){
        int q = wm*32 + mf*16 + fg*4 + r;
        Ob[(size_t)q*D_ + d] = acc[mf][nf][r] * linv[mf][r];
      }
    }
}

extern "C" void kernel_launch(void* const* d_in, const int* in_sizes, int n_in,
                              void* d_out, int out_size, void* d_ws, size_t ws_size,
                              hipStream_t stream)
{
  (void)in_sizes; (void)n_in; (void)out_size; (void)ws_size;
  const float* X  = (const float*)d_in[0];
  const float* Ww = (const float*)d_in[1];
  const float* Wb = (const float*)d_in[2];
  const float* Uw = (const float*)d_in[3];
  const float* Ub = (const float*)d_in[4];
  float* out = (float*)d_out;

  char* ws = (char*)d_ws;
  size_t off = 0;
  uint16_t* Xf = (uint16_t*)(ws + off); off += (size_t)M_TOTAL*D_*2;  // f16 [M][512]
  uint16_t* XT = (uint16_t*)(ws + off); off += (size_t)B_*D_*S_*2;    // f16 [B][512][2048]
  uint16_t* WT = (uint16_t*)(ws + off); off += (size_t)NPROJ*D_*2;    // f16 [1024][512]
  uint16_t* Qf = (uint16_t*)(ws + off); off += (size_t)M_TOTAL*U_*2;  // f16 [M][512]
  uint16_t* Kf = (uint16_t*)(ws + off); off += (size_t)M_TOTAL*U_*2;

  prep_w<<<dim3((NPROJ*D_)/256), 256, 0, stream>>>(Ww, Uw, WT);
  prep_x<<<dim3(S_/32, D_/32, B_), 256, 0, stream>>>(X, Xf, XT);

  gemm_proj<<<dim3(NPROJ/256, M_TOTAL/256, 1), 512, 0, stream>>>(
      Xf, D_, WT, D_, Qf, Kf, Wb, Ub, D_);

  flash_attn<<<dim3(B_ * (S_/QBLK)), 512, 0, stream>>>(Qf, Kf, XT, out);
}